// Round 1
// baseline (324.502 us; speedup 1.0000x reference)
//
#include <hip/hip_runtime.h>
#include <hip/hip_cooperative_groups.h>

namespace cg = cooperative_groups;

// Problem constants (from reference)
#define B_    16
#define N1_   512
#define N2_   512
#define F_    1024
#define HID_  512
#define DEG_  32
#define NNZ_  (B_ * N1_ * DEG_)   // 262144
#define NROWS (B_ * N2_)          // 8192
#define GRID_ 1024                // 4 blocks/CU on 256 CUs -> co-resident

// ----- Algebraic reduction (unchanged from previous session) -----
// w[n] = (q1[b,i] + q2[b,j]) . v  with q1 = t1 W1^T + b1, q2 = t2 W2^T + b2.
// Within a softmax segment (fixed b,i) everything except t2[b,j].(W2^T v) is
// constant, and softmax is shift-invariant per segment => only
//   s2[b,j] = t2[b,j,:] . u2,  u2 = W2^T v
// matters. t1 / W1 / b1 / b2 are never read.
//
// ----- This round: fuse the 3 kernels into ONE cooperative kernel -----
// Phase 1: u2[f] (one f per block: 2 strided loads/thread + reduce tree;
//          replaces the 32-block, 64-deep latency-bound k_partial)
// Phase 2: s2[r] = t2[r,:] . u2   (8 rows/block, reads finished u2: 4 KB/block
//          instead of re-reducing 32 KB of partials per block)
// Phase 3: 32-wide segment softmax (segments are 32 consecutive nnz by
//          construction of idx_b/idx_i)
// grid.sync() provides the cross-phase barrier + device-scope visibility.

__global__ __launch_bounds__(256, 4) void k_fused(
        const float* __restrict__ W2,     // (512, 1024) f32 row-major
        const float* __restrict__ v,      // (512,) f32
        const float* __restrict__ t2,     // (8192, 1024) f32 row-major
        const int*   __restrict__ idx_b,  // (NNZ,)
        const int*   __restrict__ idx_j,  // (NNZ,)
        float* __restrict__ u2,           // ws: (1024,) f32
        float* __restrict__ s2,           // ws: (8192,) f32
        float* __restrict__ out) {        // (NNZ,) f32
    cg::grid_group grid = cg::this_grid();
    const int tid  = threadIdx.x;
    const int wave = tid >> 6;
    const int lane = tid & 63;

    __shared__ float u[F_];    // phase 2: u2 staged in LDS (4 KB)
    __shared__ float red[4];   // phase 1: per-wave partials

    // ---- Phase 1: u2[f] = sum_{h<512} W2[h,f] * v[h]; f = blockIdx.x ----
    {
        const int f = blockIdx.x;
        float acc = W2[(size_t)tid * F_ + f] * v[tid]
                  + W2[(size_t)(tid + 256) * F_ + f] * v[tid + 256];
        #pragma unroll
        for (int off = 32; off >= 1; off >>= 1) acc += __shfl_xor(acc, off, 64);
        if (lane == 0) red[wave] = acc;
        __syncthreads();
        if (tid == 0) u2[f] = red[0] + red[1] + red[2] + red[3];
    }

    grid.sync();   // u2 complete + visible device-wide

    // ---- Phase 2: s2[r] = t2[r,:] . u2 ; 8 rows per block ----
    {
        ((float4*)u)[tid] = ((const float4*)u2)[tid];   // 256 x 16B, L2-hot
        __syncthreads();
        #pragma unroll
        for (int rr = 0; rr < 2; ++rr) {
            const int r = blockIdx.x * 8 + wave * 2 + rr;
            const float4* row = (const float4*)(t2 + (size_t)r * F_);
            float acc = 0.f;
            #pragma unroll
            for (int k = 0; k < 4; ++k) {
                const int c = k * 64 + lane;        // float4 index in [0,256)
                float4 raw = row[c];                // coalesced 16B/lane
                const float* uf = &u[c * 4];        // ds_read_b128, conflict-free
                acc += raw.x * uf[0];
                acc += raw.y * uf[1];
                acc += raw.z * uf[2];
                acc += raw.w * uf[3];
            }
            #pragma unroll
            for (int off = 32; off >= 1; off >>= 1) acc += __shfl_xor(acc, off, 64);
            if (lane == 0) s2[r] = acc;
        }
    }

    grid.sync();   // s2 complete + visible device-wide

    // ---- Phase 3: segment softmax, 256 nnz per block ----
    {
        const int n = blockIdx.x * 256 + tid;
        const int b = idx_b[n];
        const int j = idx_j[n];
        const float w = s2[b * N2_ + j];
        float m = w;
        #pragma unroll
        for (int off = 16; off >= 1; off >>= 1) m = fmaxf(m, __shfl_xor(m, off, 32));
        const float e = __expf(w - m);
        float s = e;
        #pragma unroll
        for (int off = 16; off >= 1; off >>= 1) s += __shfl_xor(s, off, 32);
        out[n] = e / s;
    }
}

// ---------------- Fallback path (non-cooperative), known-good ----------------

__global__ __launch_bounds__(256) void k_u2(
        const float* __restrict__ W2, const float* __restrict__ v,
        float* __restrict__ u2) {
    const int tid  = threadIdx.x;
    const int wave = tid >> 6;
    const int lane = tid & 63;
    __shared__ float red[4];
    const int f = blockIdx.x;
    float acc = W2[(size_t)tid * F_ + f] * v[tid]
              + W2[(size_t)(tid + 256) * F_ + f] * v[tid + 256];
    #pragma unroll
    for (int off = 32; off >= 1; off >>= 1) acc += __shfl_xor(acc, off, 64);
    if (lane == 0) red[wave] = acc;
    __syncthreads();
    if (tid == 0) u2[f] = red[0] + red[1] + red[2] + red[3];
}

__global__ __launch_bounds__(256) void k_rowdot2(
        const float* __restrict__ t2, const float* __restrict__ u2,
        float* __restrict__ s2) {
    __shared__ float u[F_];
    const int tid  = threadIdx.x;
    const int wave = tid >> 6;
    const int lane = tid & 63;
    ((float4*)u)[tid] = ((const float4*)u2)[tid];
    __syncthreads();
    #pragma unroll
    for (int rr = 0; rr < 2; ++rr) {
        const int r = blockIdx.x * 8 + wave * 2 + rr;
        const float4* row = (const float4*)(t2 + (size_t)r * F_);
        float acc = 0.f;
        #pragma unroll
        for (int k = 0; k < 4; ++k) {
            const int c = k * 64 + lane;
            float4 raw = row[c];
            const float* uf = &u[c * 4];
            acc += raw.x * uf[0];
            acc += raw.y * uf[1];
            acc += raw.z * uf[2];
            acc += raw.w * uf[3];
        }
        #pragma unroll
        for (int off = 32; off >= 1; off >>= 1) acc += __shfl_xor(acc, off, 64);
        if (lane == 0) s2[r] = acc;
    }
}

__global__ __launch_bounds__(256) void k_softmax(
        const int* __restrict__ idx_b, const int* __restrict__ idx_j,
        const float* __restrict__ s2, float* __restrict__ out) {
    const int n = blockIdx.x * 256 + threadIdx.x;
    const int b = idx_b[n];
    const int j = idx_j[n];
    const float w = s2[b * N2_ + j];
    float m = w;
    #pragma unroll
    for (int off = 16; off >= 1; off >>= 1) m = fmaxf(m, __shfl_xor(m, off, 32));
    const float e = __expf(w - m);
    float s = e;
    #pragma unroll
    for (int off = 16; off >= 1; off >>= 1) s += __shfl_xor(s, off, 32);
    out[n] = e / s;
}

extern "C" void kernel_launch(void* const* d_in, const int* in_sizes, int n_in,
                              void* d_out, int out_size, void* d_ws, size_t ws_size,
                              hipStream_t stream) {
    // setup_inputs order: t1, t2, idx_b, idx_i, idx_j, W1, b1, W2, b2, v
    const float* t2    = (const float*)d_in[1];
    const int*   idx_b = (const int*)d_in[2];
    const int*   idx_j = (const int*)d_in[4];
    const float* W2    = (const float*)d_in[7];
    const float* v     = (const float*)d_in[9];

    float* u2  = (float*)d_ws;        // 1024 floats = 4 KB
    float* s2  = u2 + F_;             // 8192 floats = 32 KB
    float* out = (float*)d_out;

    void* args[] = {(void*)&W2, (void*)&v, (void*)&t2, (void*)&idx_b,
                    (void*)&idx_j, (void*)&u2, (void*)&s2, (void*)&out};
    hipError_t err = hipLaunchCooperativeKernel(
        (const void*)k_fused, dim3(GRID_), dim3(256), args, 0, stream);

    if (err != hipSuccess) {
        // Cooperative launch rejected (e.g. under capture) -> known-good 3-kernel path
        k_u2     <<<F_,         256, 0, stream>>>(W2, v, u2);
        k_rowdot2<<<NROWS / 8,  256, 0, stream>>>(t2, u2, s2);
        k_softmax<<<NNZ_ / 256, 256, 0, stream>>>(idx_b, idx_j, s2, out);
    }
}

// Round 2
// 111.483 us; speedup vs baseline: 2.9108x; 2.9108x over previous
//
#include <hip/hip_runtime.h>

// Problem constants (from reference)
#define B_    16
#define N1_   512
#define N2_   512
#define F_    1024
#define HID_  512
#define DEG_  32
#define NNZ_  (B_ * N1_ * DEG_)   // 262144
#define NROWS (B_ * N2_)          // 8192
#define RB_   16                  // h-slices for k_partial (32 h each)

// ----- Algebraic reduction (unchanged) -----
// w[n] = (q1[b,i] + q2[b,j]) . v  with q1 = t1 W1^T + b1, q2 = t2 W2^T + b2.
// Within a softmax segment (fixed b,i) everything except t2[b,j].(W2^T v) is
// constant, and softmax is shift-invariant per segment => only
//   s2[b,j] = t2[b,j,:] . u2,  u2 = W2^T v
// matters. t1 / W1 / b1 / b2 are never read.
//
// R1 lesson: cooperative grid.sync() costs ~100 us per barrier on gfx950 at
// 1024 WGs (k_fused: 214 us, VALUBusy 0.6%). Launch boundaries in the captured
// graph are far cheaper. Back to 3 launches; optimize each.

// Kernel A: h-sliced partials of u2 = W2^T v.
// partial[rb*1024 + f] = sum_{h in [rb*32, rb*32+32)} W2[h, f] * v[h]
// grid = 64 blocks (rb in [0,16) x cb in [0,4)), block = 256.
// vs round-0: 2x blocks, half the serial load chain (32 vs 64) -> ~2x faster
// (latency-bound; only 2 MB of traffic).
__global__ __launch_bounds__(256) void k_partial(
        const float* __restrict__ W2,   // (512, 1024) f32 row-major
        const float* __restrict__ v,    // (512,) f32
        float* __restrict__ partial) {  // (RB_, 1024) f32
    const int cb = blockIdx.x & 3;
    const int rb = blockIdx.x >> 2;
    const int f  = cb * 256 + threadIdx.x;

    __shared__ float vs[32];
    if (threadIdx.x < 32) vs[threadIdx.x] = v[rb * 32 + threadIdx.x];
    __syncthreads();

    const float* w = W2 + (size_t)rb * 32 * F_ + f;
    float acc = 0.f;
    #pragma unroll 8
    for (int h = 0; h < 32; ++h) acc += w[(size_t)h * F_] * vs[h];
    partial[rb * F_ + f] = acc;
}

// Kernel B: finalize u2 into LDS, then s2[r] = t2[r,:] . u2.
// 4 waves x 2 rows = 8 rows/block; grid = NROWS/8 = 1024 blocks, block = 256.
// t2 rows are prefetched into registers BEFORE the u2 reduce so the mandatory
// 33.5 MB HBM stream starts immediately; the L2-hot partial reduce (64 KB)
// hides under it.
__global__ __launch_bounds__(256) void k_rowdot(
        const float* __restrict__ t2,       // (8192, 1024) f32 row-major
        const float* __restrict__ partial,  // (RB_, 1024) f32
        float* __restrict__ s2) {           // (8192,) f32
    __shared__ float u[F_];
    const int tid  = threadIdx.x;
    const int wave = tid >> 6;
    const int lane = tid & 63;

    // Issue the t2 register prefetch first (8 x 16B/lane, coalesced).
    float4 raw0[4], raw1[4];
    {
        const int r0 = blockIdx.x * 8 + wave * 2;
        const float4* row0 = (const float4*)(t2 + (size_t)r0 * F_);
        const float4* row1 = (const float4*)(t2 + (size_t)(r0 + 1) * F_);
        #pragma unroll
        for (int k = 0; k < 4; ++k) raw0[k] = row0[k * 64 + lane];
        #pragma unroll
        for (int k = 0; k < 4; ++k) raw1[k] = row1[k * 64 + lane];
    }

    // Reduce the RB_ partials -> u2 (each thread owns one float4 of u); L2-hot.
    {
        const float4* p4 = (const float4*)partial;
        float4 a4 = make_float4(0.f, 0.f, 0.f, 0.f);
        #pragma unroll
        for (int rb = 0; rb < RB_; ++rb) {
            float4 t = p4[rb * 256 + tid];
            a4.x += t.x; a4.y += t.y; a4.z += t.z; a4.w += t.w;
        }
        ((float4*)u)[tid] = a4;
    }
    __syncthreads();

    float acc0 = 0.f, acc1 = 0.f;
    #pragma unroll
    for (int k = 0; k < 4; ++k) {
        const int c = k * 64 + lane;          // float4 index in [0,256)
        const float* uf = &u[c * 4];          // ds_read_b128, conflict-free
        acc0 += raw0[k].x * uf[0];
        acc0 += raw0[k].y * uf[1];
        acc0 += raw0[k].z * uf[2];
        acc0 += raw0[k].w * uf[3];
        acc1 += raw1[k].x * uf[0];
        acc1 += raw1[k].y * uf[1];
        acc1 += raw1[k].z * uf[2];
        acc1 += raw1[k].w * uf[3];
    }
    #pragma unroll
    for (int off = 32; off >= 1; off >>= 1) {
        acc0 += __shfl_xor(acc0, off, 64);
        acc1 += __shfl_xor(acc1, off, 64);
    }
    if (lane == 0) {
        const int r0 = blockIdx.x * 8 + wave * 2;
        s2[r0]     = acc0;
        s2[r0 + 1] = acc1;
    }
}

// Kernel C: gather + segment softmax. Segments are 32 consecutive nnz
// (idx_b = repeat, idx_i = tile(repeat) by construction), so each 32-lane
// group handles exactly one segment.
// grid = NNZ/256 = 1024 blocks, block = 256.
__global__ __launch_bounds__(256) void k_softmax(
        const int* __restrict__ idx_b,
        const int* __restrict__ idx_j,
        const float* __restrict__ s2,
        float* __restrict__ out) {
    const int n = blockIdx.x * 256 + threadIdx.x;
    const int b = idx_b[n];
    const int j = idx_j[n];
    const float w = s2[b * N2_ + j];

    float m = w;
    #pragma unroll
    for (int off = 16; off >= 1; off >>= 1) m = fmaxf(m, __shfl_xor(m, off, 32));
    const float e = __expf(w - m);
    float s = e;
    #pragma unroll
    for (int off = 16; off >= 1; off >>= 1) s += __shfl_xor(s, off, 32);
    out[n] = e / s;
}

extern "C" void kernel_launch(void* const* d_in, const int* in_sizes, int n_in,
                              void* d_out, int out_size, void* d_ws, size_t ws_size,
                              hipStream_t stream) {
    // setup_inputs order: t1, t2, idx_b, idx_i, idx_j, W1, b1, W2, b2, v
    const float* t2    = (const float*)d_in[1];
    const int*   idx_b = (const int*)d_in[2];
    const int*   idx_j = (const int*)d_in[4];
    const float* W2    = (const float*)d_in[7];
    const float* v     = (const float*)d_in[9];

    float* partial = (float*)d_ws;            // RB_*1024 floats = 64 KB
    float* s2      = partial + RB_ * F_;      // 8192 floats    = 32 KB

    k_partial<<<RB_ * 4,     256, 0, stream>>>(W2, v, partial);
    k_rowdot <<<NROWS / 8,   256, 0, stream>>>(t2, partial, s2);
    k_softmax<<<NNZ_ / 256,  256, 0, stream>>>(idx_b, idx_j, s2,
                                               (float*)d_out);
}